// Round 1
// baseline (2184.830 us; speedup 1.0000x reference)
//
#include <hip/hip_runtime.h>
#include <math.h>

#define ATT_SCALE 0.17677669529663687f  // 32^-0.5

static __device__ __forceinline__ float gelu_exact(float v){
    return 0.5f * v * (1.0f + erff(v * 0.70710678118654752f));
}

// ---------------- bias table expansion -> ws[(h*512+qg)*64+k] ----------------
__global__ __launch_bounds__(256) void k_bias(const float* __restrict__ table,
                                              float* __restrict__ bias){
    int id = blockIdx.x * 256 + threadIdx.x;
    if (id >= 6 * 512 * 64) return;
    int k  = id & 63;
    int qg = (id >> 6) & 511;
    int h  = id >> 15;
    int qi = qg >> 6, qj = (qg >> 3) & 7, qk = qg & 7;
    int ki = k >> 4,  kj = (k >> 2) & 3,  kk = k & 3;
    int r0 = (qi >> 1) - ki + 3;
    int r1 = (qj >> 1) - kj + 3;
    int r2 = (qk >> 1) - kk + 3;
    bias[id] = table[((r0 * 7 + r1) * 7 + r2) * 6 + h];
}

// ---------------- deconv path: d_out = sc (full overwrite) ----------------
__global__ __launch_bounds__(256) void k_deconv(const float* __restrict__ x,
    const float* __restrict__ eg, const float* __restrict__ eb,
    const float* __restrict__ w, const float* __restrict__ db,
    float* __restrict__ out){
    __shared__ float xe[32][196];
    __shared__ float mu_s[32], rs_s[32];
    const int tid = threadIdx.x;
    const int ci0 = blockIdx.x * 32;

    for (int idx = tid; idx < 32 * 192; idx += 256){
        int t = idx / 192, j = idx - t * 192;
        xe[t][j] = x[(ci0 + t) * 192 + j];
    }
    __syncthreads();
    if (tid < 32){
        float s = 0.f, ss = 0.f;
        for (int j = 0; j < 192; j++){ float v = xe[tid][j]; s += v; ss += v * v; }
        float mu  = s * (1.f / 192.f);
        float var = ss * (1.f / 192.f) - mu * mu;
        mu_s[tid] = mu; rs_s[tid] = rsqrtf(var + 1e-5f);
    }
    __syncthreads();
    for (int idx = tid; idx < 32 * 192; idx += 256){
        int t = idx / 192, j = idx - t * 192;
        xe[t][j] = (xe[t][j] - mu_s[t]) * rs_s[t] * eg[j] + eb[j];
    }
    __syncthreads();

    for (int r = 0; r < 6; r++){
        int u  = tid + 256 * r;          // 0..1535 = 16 token-pairs x 96 out-ch
        int t2 = u / 96, o = u - t2 * 96;
        int ta = t2 * 2;
        float acc[2][8];
        #pragma unroll
        for (int i = 0; i < 2; i++)
            #pragma unroll
            for (int j = 0; j < 8; j++) acc[i][j] = 0.f;

        for (int cc = 0; cc < 192; cc++){
            float x0 = xe[ta][cc], x1 = xe[ta + 1][cc];
            const float* wp = w + (cc * 96 + o) * 8;
            float4 wa = *(const float4*)wp;
            float4 wb = *(const float4*)(wp + 4);
            acc[0][0] += x0 * wa.x; acc[0][1] += x0 * wa.y;
            acc[0][2] += x0 * wa.z; acc[0][3] += x0 * wa.w;
            acc[0][4] += x0 * wb.x; acc[0][5] += x0 * wb.y;
            acc[0][6] += x0 * wb.z; acc[0][7] += x0 * wb.w;
            acc[1][0] += x1 * wa.x; acc[1][1] += x1 * wa.y;
            acc[1][2] += x1 * wa.z; acc[1][3] += x1 * wa.w;
            acc[1][4] += x1 * wb.x; acc[1][5] += x1 * wb.y;
            acc[1][6] += x1 * wb.z; acc[1][7] += x1 * wb.w;
        }
        float bo = db[o];
        #pragma unroll
        for (int t = 0; t < 2; t++){
            int ci  = ci0 + ta + t;
            int bb  = ci >> 14;
            int rem = ci & 16383;
            int s = rem >> 10, hh = (rem >> 5) & 31, wc = rem & 31;
            int ftb = ((bb * 32 + 2 * s) * 64 + 2 * hh) * 64 + 2 * wc;
            #pragma unroll
            for (int ijk = 0; ijk < 8; ijk++){
                int i = ijk >> 2, j = (ijk >> 1) & 1, k = ijk & 1;
                out[(ftb + i * 4096 + j * 64 + k) * 96 + o] = acc[t][ijk] + bo;
            }
        }
    }
}

// ---------------- fused windowed cross-attention: d_out = sc + attn_out ----------------
__global__ __launch_bounds__(384) void k_attn(
    const float* __restrict__ x,  const float* __restrict__ xd,
    const float* __restrict__ g1, const float* __restrict__ b1v,
    const float* __restrict__ Wkv, const float* __restrict__ bkv,
    const float* __restrict__ Wq,  const float* __restrict__ bq,
    const float* __restrict__ Wp,  const float* __restrict__ bpj,
    const float* __restrict__ bias, float* __restrict__ yout){
    __shared__ float Ks[64][192];     // 48 KB
    __shared__ float Vs[64][192];     // 48 KB
    __shared__ float qb[64][196];     // 49 KB (x-stage -> q -> attn-out)
    __shared__ float mu_s[64], rs_s[64];
    const int tid  = threadIdx.x;
    const int win  = blockIdx.x;
    const int b    = win >> 8;
    const int wrem = win & 255;
    const int sw = wrem >> 6, hw = (wrem >> 3) & 7, ww = wrem & 7;

    // A0: stage coarse x window into qb
    for (int idx = tid; idx < 64 * 192; idx += 384){
        int n = idx / 192, j = idx - n * 192;
        int si = n >> 4, hi = (n >> 2) & 3, wi = n & 3;
        int ci = ((b * 16 + 4 * sw + si) * 32 + 4 * hw + hi) * 32 + 4 * ww + wi;
        qb[n][j] = x[ci * 192 + j];
    }
    __syncthreads();
    // A1: LN statistics
    if (tid < 64){
        float s = 0.f, ss = 0.f;
        for (int j = 0; j < 192; j++){ float v = qb[tid][j]; s += v; ss += v * v; }
        float mu  = s * (1.f / 192.f);
        float var = ss * (1.f / 192.f) - mu * mu;
        mu_s[tid] = mu; rs_s[tid] = rsqrtf(var + 1e-5f);
    }
    __syncthreads();
    // A2: normalize in place
    for (int idx = tid; idx < 64 * 192; idx += 384){
        int n = idx / 192, j = idx - n * 192;
        qb[n][j] = (qb[n][j] - mu_s[n]) * rs_s[n] * g1[j] + b1v[j];
    }
    __syncthreads();
    // A3: K,V = ln_x @ Wkv + bkv  (register tile 8n x 8c)
    {
        const int nt = tid / 48, ct = tid - nt * 48;
        const int n0 = nt * 8, c0 = ct * 8;
        float acc[8][8];
        #pragma unroll
        for (int i = 0; i < 8; i++)
            #pragma unroll
            for (int uu = 0; uu < 8; uu++) acc[i][uu] = 0.f;
        for (int j = 0; j < 192; j++){
            const float* wp = Wkv + j * 384 + c0;
            float4 wa = *(const float4*)wp;
            float4 wb = *(const float4*)(wp + 4);
            float wv[8] = {wa.x, wa.y, wa.z, wa.w, wb.x, wb.y, wb.z, wb.w};
            float xr[8];
            #pragma unroll
            for (int i = 0; i < 8; i++) xr[i] = qb[n0 + i][j];
            #pragma unroll
            for (int i = 0; i < 8; i++){
                #pragma unroll
                for (int uu = 0; uu < 8; uu++) acc[i][uu] += xr[i] * wv[uu];
            }
        }
        if (c0 < 192){
            #pragma unroll
            for (int i = 0; i < 8; i++)
                #pragma unroll
                for (int uu = 0; uu < 8; uu++)
                    Ks[n0 + i][c0 + uu] = acc[i][uu] + bkv[c0 + uu];
        } else {
            const int cv = c0 - 192;
            #pragma unroll
            for (int i = 0; i < 8; i++)
                #pragma unroll
                for (int uu = 0; uu < 8; uu++)
                    Vs[n0 + i][cv + uu] = acc[i][uu] + bkv[c0 + uu];
        }
    }
    __syncthreads();

    const int h   = tid >> 6;        // wave = head
    const int lq  = tid & 63;        // lane = query row in tile
    const int h32 = h * 32;
    const int cB5 = tid % 96, qrowB5 = tid / 96;

    for (int qt = 0; qt < 8; qt++){
        // ---- B1: q tile (64x192) -> qb, register tile 4q x 8c, global x_ds/Wq ----
        {
            const int qtile = tid / 24, ctile = tid - qtile * 24;
            const int q0 = qtile * 4, c0 = ctile * 8;
            float qacc[4][8];
            #pragma unroll
            for (int i = 0; i < 4; i++)
                #pragma unroll
                for (int uu = 0; uu < 8; uu++) qacc[i][uu] = 0.f;
            int ftrow[4];
            #pragma unroll
            for (int i = 0; i < 4; i++){
                int ql = q0 + i;
                ftrow[i] = ((b * 32 + 8 * sw + qt) * 64 + 8 * hw + (ql >> 3)) * 64 + 8 * ww + (ql & 7);
            }
            for (int j0 = 0; j0 < 96; j0 += 4){
                float4 xv[4];
                #pragma unroll
                for (int i = 0; i < 4; i++) xv[i] = *(const float4*)(xd + ftrow[i] * 96 + j0);
                #pragma unroll
                for (int jj = 0; jj < 4; jj++){
                    const float* wp = Wq + (j0 + jj) * 192 + c0;
                    float4 wa = *(const float4*)wp;
                    float4 wb = *(const float4*)(wp + 4);
                    float wv[8] = {wa.x, wa.y, wa.z, wa.w, wb.x, wb.y, wb.z, wb.w};
                    #pragma unroll
                    for (int i = 0; i < 4; i++){
                        float xs = (jj == 0) ? xv[i].x : ((jj == 1) ? xv[i].y : ((jj == 2) ? xv[i].z : xv[i].w));
                        #pragma unroll
                        for (int uu = 0; uu < 8; uu++) qacc[i][uu] += xs * wv[uu];
                    }
                }
            }
            #pragma unroll
            for (int i = 0; i < 4; i++)
                #pragma unroll
                for (int uu = 0; uu < 8; uu++)
                    qb[q0 + i][c0 + uu] = (qacc[i][uu] + bq[c0 + uu]) * ATT_SCALE;
        }
        __syncthreads();
        // ---- B2/B3: scores + bias + softmax + PV (thread = (q,row head)) ----
        float o[32];
        float inv;
        {
            float qr[32];
            #pragma unroll
            for (int d4 = 0; d4 < 8; d4++){
                float4 t4 = *(const float4*)(&qb[lq][h32 + d4 * 4]);
                qr[d4 * 4 + 0] = t4.x; qr[d4 * 4 + 1] = t4.y;
                qr[d4 * 4 + 2] = t4.z; qr[d4 * 4 + 3] = t4.w;
            }
            float s[64];
            #pragma unroll
            for (int k = 0; k < 64; k++){
                const float* kp = &Ks[k][h32];
                float a = 0.f;
                #pragma unroll
                for (int d4 = 0; d4 < 8; d4++){
                    float4 kv4 = *(const float4*)(kp + d4 * 4);
                    a += qr[d4 * 4 + 0] * kv4.x + qr[d4 * 4 + 1] * kv4.y
                       + qr[d4 * 4 + 2] * kv4.z + qr[d4 * 4 + 3] * kv4.w;
                }
                s[k] = a;
            }
            const float* bptr = bias + (h * 512 + qt * 64 + lq) * 64;
            #pragma unroll
            for (int k4 = 0; k4 < 64; k4 += 4){
                float4 bb = *(const float4*)(bptr + k4);
                s[k4 + 0] += bb.x; s[k4 + 1] += bb.y; s[k4 + 2] += bb.z; s[k4 + 3] += bb.w;
            }
            float m = s[0];
            #pragma unroll
            for (int k = 1; k < 64; k++) m = fmaxf(m, s[k]);
            float sum = 0.f;
            #pragma unroll
            for (int k = 0; k < 64; k++){ float e = __expf(s[k] - m); s[k] = e; sum += e; }
            inv = 1.f / sum;
            #pragma unroll
            for (int d = 0; d < 32; d++) o[d] = 0.f;
            #pragma unroll
            for (int k = 0; k < 64; k++){
                const float* vp = &Vs[k][h32];
                float p = s[k];
                #pragma unroll
                for (int d4 = 0; d4 < 8; d4++){
                    float4 vv = *(const float4*)(vp + d4 * 4);
                    o[d4 * 4 + 0] += p * vv.x; o[d4 * 4 + 1] += p * vv.y;
                    o[d4 * 4 + 2] += p * vv.z; o[d4 * 4 + 3] += p * vv.w;
                }
            }
        }
        __syncthreads();                 // all q reads done before overwrite
        // ---- B4: attn-out -> qb ----
        #pragma unroll
        for (int d4 = 0; d4 < 8; d4++){
            float4 t4;
            t4.x = o[d4 * 4 + 0] * inv; t4.y = o[d4 * 4 + 1] * inv;
            t4.z = o[d4 * 4 + 2] * inv; t4.w = o[d4 * 4 + 3] * inv;
            *(float4*)(&qb[lq][h32 + d4 * 4]) = t4;
        }
        __syncthreads();
        // ---- B5: proj (192->96) + add sc, write y ----
        {
            float acc2[16];
            #pragma unroll
            for (int qi = 0; qi < 16; qi++) acc2[qi] = 0.f;
            for (int kk0 = 0; kk0 < 192; kk0 += 32){
                float wpr[32];
                #pragma unroll
                for (int d = 0; d < 32; d++) wpr[d] = Wp[(kk0 + d) * 96 + cB5];
                #pragma unroll
                for (int qi = 0; qi < 16; qi++){
                    const int qq = qrowB5 * 16 + qi;
                    const float* qp = &qb[qq][kk0];
                    float part = 0.f;
                    #pragma unroll
                    for (int d4 = 0; d4 < 8; d4++){
                        float4 qv = *(const float4*)(qp + d4 * 4);
                        part += qv.x * wpr[d4 * 4 + 0] + qv.y * wpr[d4 * 4 + 1]
                              + qv.z * wpr[d4 * 4 + 2] + qv.w * wpr[d4 * 4 + 3];
                    }
                    acc2[qi] += part;
                }
            }
            const float bpc = bpj[cB5];
            #pragma unroll
            for (int qi = 0; qi < 16; qi++){
                const int qq = qrowB5 * 16 + qi;
                const int ft = ((b * 32 + 8 * sw + qt) * 64 + 8 * hw + (qq >> 3)) * 64 + 8 * ww + (qq & 7);
                float* yp = yout + ft * 96 + cB5;
                *yp = *yp + acc2[qi] + bpc;      // y = sc + attn_out
            }
        }
        __syncthreads();
    }
}

// ---------------- MLP: d_out = y + W2(gelu(W1 ln(y)+b1))+b2, in place ----------------
__global__ __launch_bounds__(256) void k_mlp(
    const float* __restrict__ y, const float* __restrict__ g2, const float* __restrict__ b2v,
    const float* __restrict__ W1, const float* __restrict__ b1m,
    const float* __restrict__ W2, const float* __restrict__ b2m,
    float* __restrict__ outp){
    __shared__ float yn[64][97];
    __shared__ float hb[64][97];
    __shared__ float mu_s[64], rs_s[64];
    const int tid = threadIdx.x;
    const int t0  = blockIdx.x * 64;

    for (int idx = tid; idx < 64 * 96; idx += 256){
        int t = idx / 96, j = idx - t * 96;
        yn[t][j] = y[(t0 + t) * 96 + j];
    }
    __syncthreads();
    if (tid < 64){
        float s = 0.f, ss = 0.f;
        for (int j = 0; j < 96; j++){ float v = yn[tid][j]; s += v; ss += v * v; }
        float mu  = s * (1.f / 96.f);
        float var = ss * (1.f / 96.f) - mu * mu;
        mu_s[tid] = mu; rs_s[tid] = rsqrtf(var + 1e-5f);
    }
    __syncthreads();
    for (int idx = tid; idx < 64 * 96; idx += 256){
        int t = idx / 96, j = idx - t * 96;
        yn[t][j] = (yn[t][j] - mu_s[t]) * rs_s[t] * g2[j] + b2v[j];
    }
    __syncthreads();

    const int tt = tid >> 4, cc = tid & 15;
    const int ta = tt * 4, ca = cc * 6;
    float oacc[4][6];
    #pragma unroll
    for (int i = 0; i < 4; i++)
        #pragma unroll
        for (int u = 0; u < 6; u++) oacc[i][u] = 0.f;

    for (int ch = 0; ch < 4; ch++){
        float hacc[4][6];
        #pragma unroll
        for (int i = 0; i < 4; i++)
            #pragma unroll
            for (int u = 0; u < 6; u++) hacc[i][u] = 0.f;
        for (int j = 0; j < 96; j++){
            float xr[4];
            #pragma unroll
            for (int i = 0; i < 4; i++) xr[i] = yn[ta + i][j];
            const float* wp = W1 + j * 384 + ch * 96 + ca;
            float wr[6];
            #pragma unroll
            for (int u = 0; u < 6; u++) wr[u] = wp[u];
            #pragma unroll
            for (int i = 0; i < 4; i++)
                #pragma unroll
                for (int u = 0; u < 6; u++) hacc[i][u] += xr[i] * wr[u];
        }
        #pragma unroll
        for (int i = 0; i < 4; i++)
            #pragma unroll
            for (int u = 0; u < 6; u++){
                float v = hacc[i][u] + b1m[ch * 96 + ca + u];
                hb[ta + i][ca + u] = gelu_exact(v);
            }
        __syncthreads();
        for (int j = 0; j < 96; j++){
            float hr[4];
            #pragma unroll
            for (int i = 0; i < 4; i++) hr[i] = hb[ta + i][j];
            const float* wp = W2 + (ch * 96 + j) * 96 + ca;
            float wr[6];
            #pragma unroll
            for (int u = 0; u < 6; u++) wr[u] = wp[u];
            #pragma unroll
            for (int i = 0; i < 4; i++)
                #pragma unroll
                for (int u = 0; u < 6; u++) oacc[i][u] += hr[i] * wr[u];
        }
        __syncthreads();
    }
    #pragma unroll
    for (int i = 0; i < 4; i++){
        const int tok = t0 + ta + i;
        #pragma unroll
        for (int u = 0; u < 6; u++){
            const int c = ca + u;
            float yv = y[tok * 96 + c];
            outp[tok * 96 + c] = yv + oacc[i][u] + b2m[c];
        }
    }
}

extern "C" void kernel_launch(void* const* d_in, const int* in_sizes, int n_in,
                              void* d_out, int out_size, void* d_ws, size_t ws_size,
                              hipStream_t stream){
    const float* x    = (const float*)d_in[0];
    const float* xd   = (const float*)d_in[1];
    const float* g1   = (const float*)d_in[2];
    const float* b1v  = (const float*)d_in[3];
    const float* Wkv  = (const float*)d_in[4];
    const float* bkv  = (const float*)d_in[5];
    const float* Wq   = (const float*)d_in[6];
    const float* bq   = (const float*)d_in[7];
    const float* Wp   = (const float*)d_in[8];
    const float* bpj  = (const float*)d_in[9];
    const float* btab = (const float*)d_in[10];
    const float* eg   = (const float*)d_in[11];
    const float* eb   = (const float*)d_in[12];
    const float* dw   = (const float*)d_in[13];
    const float* db   = (const float*)d_in[14];
    const float* g2   = (const float*)d_in[15];
    const float* b2v  = (const float*)d_in[16];
    const float* W1   = (const float*)d_in[17];
    const float* b1m  = (const float*)d_in[18];
    const float* W2   = (const float*)d_in[19];
    const float* b2m  = (const float*)d_in[20];
    (void)in_sizes; (void)n_in; (void)out_size; (void)ws_size;

    float* out  = (float*)d_out;
    float* bias = (float*)d_ws;   // 6*512*64 f32 = 786 KB

    k_bias  <<<768, 256, 0, stream>>>(btab, bias);
    k_deconv<<<1024, 256, 0, stream>>>(x, eg, eb, dw, db, out);
    k_attn  <<<512, 384, 0, stream>>>(x, xd, g1, b1v, Wkv, bkv, Wq, bq, Wp, bpj, bias, out);
    k_mlp   <<<4096, 256, 0, stream>>>(out, g2, b2v, W1, b1m, W2, b2m, out);
}

// Round 2
// 409.234 us; speedup vs baseline: 5.3388x; 5.3388x over previous
//
#include <hip/hip_runtime.h>
#include <math.h>

#define ATT_SCALE 0.17677669529663687f  // 32^-0.5

typedef __bf16 bf16x8 __attribute__((ext_vector_type(8)));
typedef __bf16 bf16x4 __attribute__((ext_vector_type(4)));
typedef float  f32x4  __attribute__((ext_vector_type(4)));

#define MFMA16(a,b,c) __builtin_amdgcn_mfma_f32_16x16x32_bf16(a,b,c,0,0,0)

// ws layout: [0,786432) f32 expanded bias; then bf16 swizzled weights
#define BIAS_BYTES 786432
#define WKV_OFF 0        // 192x384  kt6  NRT24
#define WQ_OFF  73728    // 96x192   kt3  NRT12 (pre-scaled)
#define WP_OFF  92160    // 192x96   kt6  NRT6
#define WD_OFF  110592   // 192x768  kt6  NRT48
#define W1_OFF  258048   // 96x384   kt3  NRT24
#define W2_OFF  294912   // 384x96   kt12 NRT6
#define NSWZ    331776

static __device__ __forceinline__ float gelu_exact(float v){
    return 0.5f * v * (1.0f + erff(v * 0.70710678118654752f));
}

static __device__ __forceinline__ bf16x8 afrag(const __bf16* w, int NRT, int kt, int rt, int lane){
    return ((const bf16x8*)w)[(kt*NRT + rt)*64 + lane];
}

// ---------------- prep: bias expand + weight bf16 swizzle ----------------
__global__ __launch_bounds__(256) void k_prep(const float* __restrict__ table,
    const float* __restrict__ Wkv, const float* __restrict__ Wq,
    const float* __restrict__ Wp,  const float* __restrict__ Wd,
    const float* __restrict__ W1,  const float* __restrict__ W2,
    float* __restrict__ bias, __bf16* __restrict__ wsw){
    int id = blockIdx.x * 256 + threadIdx.x;
    if (id < 196608){
        int k  = id & 63;
        int qg = (id >> 6) & 511;
        int h  = id >> 15;
        int qi = qg >> 6, qj = (qg >> 3) & 7, qk = qg & 7;
        int ki = k >> 4,  kj = (k >> 2) & 3,  kk = k & 3;
        int r0 = (qi >> 1) - ki + 3;
        int r1 = (qj >> 1) - kj + 3;
        int r2 = (qk >> 1) - kk + 3;
        bias[id] = table[((r0 * 7 + r1) * 7 + r2) * 6 + h];
        return;
    }
    id -= 196608;
    if (id >= NSWZ) return;
    const float* W; int N, NRT, off; float sc = 1.f;
    if      (id < WQ_OFF){ W = Wkv; N = 384; NRT = 24; off = WKV_OFF; }
    else if (id < WP_OFF){ W = Wq;  N = 192; NRT = 12; off = WQ_OFF; sc = ATT_SCALE; }
    else if (id < WD_OFF){ W = Wp;  N = 96;  NRT = 6;  off = WP_OFF; }
    else if (id < W1_OFF){ W = Wd;  N = 768; NRT = 48; off = WD_OFF; }
    else if (id < W2_OFF){ W = W1;  N = 384; NRT = 24; off = W1_OFF; }
    else                 { W = W2;  N = 96;  NRT = 6;  off = W2_OFF; }
    int lid  = id - off;
    int j    = lid & 7, lane = (lid >> 3) & 63, tile = lid >> 9;
    int rt   = tile % NRT, kt = tile / NRT;
    int n    = rt * 16 + (lane & 15);
    int k    = kt * 32 + (lane >> 4) * 8 + j;
    wsw[id + 0] = (__bf16)(W[k * N + n] * sc);
}

// ---------------- deconv path (MFMA): d_out = sc (full overwrite) ----------------
__global__ __launch_bounds__(512) void k_deconv(const float* __restrict__ x,
    const float* __restrict__ eg, const float* __restrict__ eb,
    const __bf16* __restrict__ wsw, const float* __restrict__ db,
    float* __restrict__ out){
    __shared__ __bf16 xe[64][200];
    const int tid = threadIdx.x, lane = tid & 63, w = tid >> 6;
    const int ci0 = blockIdx.x * 64;
    {   // LN stage -> bf16
        int row = tid >> 3, sub = tid & 7;
        const float* xp = x + (ci0 + row) * 192 + sub * 24;
        float v[24]; float s = 0.f, ss = 0.f;
        #pragma unroll
        for (int i = 0; i < 6; i++){
            float4 t = ((const float4*)xp)[i];
            v[4*i] = t.x; v[4*i+1] = t.y; v[4*i+2] = t.z; v[4*i+3] = t.w;
            s += t.x + t.y + t.z + t.w;
            ss += t.x*t.x + t.y*t.y + t.z*t.z + t.w*t.w;
        }
        #pragma unroll
        for (int m = 1; m < 8; m <<= 1){ s += __shfl_xor(s, m); ss += __shfl_xor(ss, m); }
        float mu = s * (1.f/192.f), var = ss * (1.f/192.f) - mu*mu, rs = rsqrtf(var + 1e-5f);
        #pragma unroll
        for (int i = 0; i < 3; i++){
            bf16x8 t;
            #pragma unroll
            for (int jj = 0; jj < 8; jj++){
                int c = sub*24 + 8*i + jj;
                t[jj] = (__bf16)((v[8*i+jj] - mu) * rs * eg[c] + eb[c]);
            }
            *(bf16x8*)&xe[row][sub*24 + 8*i] = t;
        }
    }
    __syncthreads();
    const int ct = w & 3, rh = w >> 2;
    const int tok = ct * 16 + (lane & 15);
    const int ci  = ci0 + tok;
    const int bb  = ci >> 14, rem = ci & 16383;
    const int sC  = rem >> 10, hC = (rem >> 5) & 31, wC = rem & 31;
    const int ftb = ((bb * 32 + 2 * sC) * 64 + 2 * hC) * 64 + 2 * wC;
    bf16x8 bfr[6];
    #pragma unroll
    for (int kt = 0; kt < 6; kt++) bfr[kt] = *(const bf16x8*)&xe[tok][kt*32 + (lane>>4)*8];
    for (int i = 0; i < 24; i++){
        int rt = rh * 24 + i;
        f32x4 acc = {0.f,0.f,0.f,0.f};
        #pragma unroll
        for (int kt = 0; kt < 6; kt++) acc = MFMA16(afrag(wsw + WD_OFF, 48, kt, rt, lane), bfr[kt], acc);
        int nb = rt * 16 + ((lane >> 4) << 2);
        int o = nb >> 3, ij0 = nb & 7;
        float bo = db[o];
        #pragma unroll
        for (int r = 0; r < 4; r++){
            int ijk = ij0 + r;
            int ft = ftb + (ijk >> 2) * 4096 + ((ijk >> 1) & 1) * 64 + (ijk & 1);
            out[ft * 96 + o] = acc[r] + bo;
        }
    }
}

// ---------------- fused windowed cross-attention (MFMA): d_out += attn ----------------
__global__ __launch_bounds__(512) void k_attn(const float* __restrict__ x,
    const float* __restrict__ xd, const float* __restrict__ g1, const float* __restrict__ b1v,
    const float* __restrict__ bkv, const float* __restrict__ bq, const float* __restrict__ bpj,
    const __bf16* __restrict__ wsw, const float* __restrict__ bias, float* __restrict__ yout){
    __shared__ __bf16 Qs[64][200];   // xln -> Q -> attn-out (aliased phases)
    __shared__ __bf16 Ks[64][200];
    __shared__ __bf16 Vt[192][72];   // V transposed [d][kv]
    __shared__ __bf16 Pw[8][16][72]; // per-wave P [q][kv]
    const int tid = threadIdx.x, lane = tid & 63, w = tid >> 6;
    const int win = blockIdx.x, b = win >> 8, wrem = win & 255;
    const int sw_ = wrem >> 6, hw_ = (wrem >> 3) & 7, ww_ = wrem & 7;

    {   // LN stage of coarse x window -> Qs (as xln)
        int row = tid >> 3, sub = tid & 7;
        int si = row >> 4, hi = (row >> 2) & 3, wi = row & 3;
        int ci = ((b * 16 + 4 * sw_ + si) * 32 + 4 * hw_ + hi) * 32 + 4 * ww_ + wi;
        const float* xp = x + ci * 192 + sub * 24;
        float v[24]; float s = 0.f, ss = 0.f;
        #pragma unroll
        for (int i = 0; i < 6; i++){
            float4 t = ((const float4*)xp)[i];
            v[4*i] = t.x; v[4*i+1] = t.y; v[4*i+2] = t.z; v[4*i+3] = t.w;
            s += t.x + t.y + t.z + t.w;
            ss += t.x*t.x + t.y*t.y + t.z*t.z + t.w*t.w;
        }
        #pragma unroll
        for (int m = 1; m < 8; m <<= 1){ s += __shfl_xor(s, m); ss += __shfl_xor(ss, m); }
        float mu = s * (1.f/192.f), var = ss * (1.f/192.f) - mu*mu, rs = rsqrtf(var + 1e-5f);
        #pragma unroll
        for (int i = 0; i < 3; i++){
            bf16x8 t;
            #pragma unroll
            for (int jj = 0; jj < 8; jj++){
                int c = sub*24 + 8*i + jj;
                t[jj] = (__bf16)((v[8*i+jj] - mu) * rs * g1[c] + b1v[c]);
            }
            *(bf16x8*)&Qs[row][sub*24 + 8*i] = t;
        }
    }
    __syncthreads();
    {   // KVproj: KV^T = Wkv^T @ xln^T ; waves 0-3 -> K rows, 4-7 -> V^T
        const int ct = w & 3, rh = w >> 2;
        const int tok = ct * 16 + (lane & 15);
        bf16x8 bfr[6];
        #pragma unroll
        for (int kt = 0; kt < 6; kt++) bfr[kt] = *(const bf16x8*)&Qs[tok][kt*32 + (lane>>4)*8];
        #pragma unroll
        for (int i = 0; i < 12; i++){
            int rt = rh * 12 + i;
            f32x4 acc = {0.f,0.f,0.f,0.f};
            #pragma unroll
            for (int kt = 0; kt < 6; kt++) acc = MFMA16(afrag(wsw + WKV_OFF, 24, kt, rt, lane), bfr[kt], acc);
            int cb = rt * 16 + ((lane >> 4) << 2);
            float4 b4 = *(const float4*)&bkv[cb];
            acc[0] += b4.x; acc[1] += b4.y; acc[2] += b4.z; acc[3] += b4.w;
            if (cb < 192){
                bf16x4 t;
                #pragma unroll
                for (int r = 0; r < 4; r++) t[r] = (__bf16)acc[r];
                *(bf16x4*)&Ks[tok][cb] = t;
            } else {
                #pragma unroll
                for (int r = 0; r < 4; r++) Vt[cb - 192 + r][tok] = (__bf16)acc[r];
            }
        }
    }
    __syncthreads();

    for (int qt = 0; qt < 8; qt++){
        {   // Qproj: Q^T = Wq^T(scaled) @ xd^T ; B-frags straight from global f32
            const int ct = w & 3, rh = w >> 2;
            const int ql = ct * 16 + (lane & 15);
            const int ft = ((b * 32 + 8 * sw_ + qt) * 64 + 8 * hw_ + (ql >> 3)) * 64 + 8 * ww_ + (ql & 7);
            bf16x8 bfr[3];
            #pragma unroll
            for (int kt = 0; kt < 3; kt++){
                const float* xp = xd + ft * 96 + kt * 32 + (lane >> 4) * 8;
                float4 t0 = *(const float4*)xp;
                float4 t1 = *(const float4*)(xp + 4);
                bf16x8 t;
                t[0]=(__bf16)t0.x; t[1]=(__bf16)t0.y; t[2]=(__bf16)t0.z; t[3]=(__bf16)t0.w;
                t[4]=(__bf16)t1.x; t[5]=(__bf16)t1.y; t[6]=(__bf16)t1.z; t[7]=(__bf16)t1.w;
                bfr[kt] = t;
            }
            #pragma unroll
            for (int i = 0; i < 6; i++){
                int rt = rh * 6 + i;
                f32x4 acc = {0.f,0.f,0.f,0.f};
                #pragma unroll
                for (int kt = 0; kt < 3; kt++) acc = MFMA16(afrag(wsw + WQ_OFF, 12, kt, rt, lane), bfr[kt], acc);
                int cb = rt * 16 + ((lane >> 4) << 2);
                float4 b4 = *(const float4*)&bq[cb];
                bf16x4 t;
                t[0] = (__bf16)(acc[0] + b4.x * ATT_SCALE);
                t[1] = (__bf16)(acc[1] + b4.y * ATT_SCALE);
                t[2] = (__bf16)(acc[2] + b4.z * ATT_SCALE);
                t[3] = (__bf16)(acc[3] + b4.w * ATT_SCALE);
                *(bf16x4*)&Qs[ql][cb] = t;
            }
        }
        __syncthreads();
        // scores + softmax + PV  (3 units per wave: unit = (head, q-coltile))
        f32x4 ov[3][2];
        #pragma unroll
        for (int ui = 0; ui < 3; ui++){
            const int u = w * 3 + ui;
            const int h = u >> 2, qct = u & 3;
            f32x4 sc[4];
            #pragma unroll
            for (int rt = 0; rt < 4; rt++){
                bf16x8 a  = *(const bf16x8*)&Ks[rt*16 + (lane & 15)][h*32 + (lane >> 4)*8];
                bf16x8 bq8 = *(const bf16x8*)&Qs[qct*16 + (lane & 15)][h*32 + (lane >> 4)*8];
                f32x4 z = {0.f,0.f,0.f,0.f};
                sc[rt] = MFMA16(a, bq8, z);
            }
            const int qg = qt * 64 + qct * 16 + (lane & 15);
            const float* bp = bias + (h * 512 + qg) * 64 + ((lane >> 4) << 2);
            #pragma unroll
            for (int rt = 0; rt < 4; rt++){
                float4 b4 = *(const float4*)(bp + rt * 16);
                sc[rt][0] += b4.x; sc[rt][1] += b4.y; sc[rt][2] += b4.z; sc[rt][3] += b4.w;
            }
            float m = sc[0][0];
            #pragma unroll
            for (int rt = 0; rt < 4; rt++)
                #pragma unroll
                for (int r = 0; r < 4; r++) m = fmaxf(m, sc[rt][r]);
            m = fmaxf(m, __shfl_xor(m, 16));
            m = fmaxf(m, __shfl_xor(m, 32));
            float sum = 0.f;
            #pragma unroll
            for (int rt = 0; rt < 4; rt++)
                #pragma unroll
                for (int r = 0; r < 4; r++){ float e = __expf(sc[rt][r] - m); sc[rt][r] = e; sum += e; }
            sum += __shfl_xor(sum, 16);
            sum += __shfl_xor(sum, 32);
            float inv = 1.f / sum;
            #pragma unroll
            for (int rt = 0; rt < 4; rt++){
                bf16x4 t;
                #pragma unroll
                for (int r = 0; r < 4; r++) t[r] = (__bf16)(sc[rt][r] * inv);
                *(bf16x4*)&Pw[w][lane & 15][rt*16 + ((lane >> 4) << 2)] = t;
            }
            #pragma unroll
            for (int dt = 0; dt < 2; dt++){
                f32x4 o = {0.f,0.f,0.f,0.f};
                #pragma unroll
                for (int kt = 0; kt < 2; kt++){
                    bf16x8 a  = *(const bf16x8*)&Vt[h*32 + dt*16 + (lane & 15)][kt*32 + (lane >> 4)*8];
                    bf16x8 pb = *(const bf16x8*)&Pw[w][lane & 15][kt*32 + (lane >> 4)*8];
                    o = MFMA16(a, pb, o);
                }
                ov[ui][dt] = o;
            }
        }
        __syncthreads();   // all Qs reads done
        #pragma unroll
        for (int ui = 0; ui < 3; ui++){
            const int u = w * 3 + ui;
            const int h = u >> 2, qct = u & 3;
            const int tok = qct * 16 + (lane & 15);
            #pragma unroll
            for (int dt = 0; dt < 2; dt++){
                int cb = h * 32 + dt * 16 + ((lane >> 4) << 2);
                bf16x4 t;
                #pragma unroll
                for (int r = 0; r < 4; r++) t[r] = (__bf16)ov[ui][dt][r];
                *(bf16x4*)&Qs[tok][cb] = t;
            }
        }
        __syncthreads();
        {   // outproj: Y^T = Wp^T @ out^T ; += into d_out (y = sc + attn)
            const int ct = w & 3, rh = w >> 2;
            const int ql = ct * 16 + (lane & 15);
            const int ft = ((b * 32 + 8 * sw_ + qt) * 64 + 8 * hw_ + (ql >> 3)) * 64 + 8 * ww_ + (ql & 7);
            bf16x8 bfr[6];
            #pragma unroll
            for (int kt = 0; kt < 6; kt++) bfr[kt] = *(const bf16x8*)&Qs[ql][kt*32 + (lane>>4)*8];
            #pragma unroll
            for (int i = 0; i < 3; i++){
                int rt = rh * 3 + i;
                f32x4 acc = {0.f,0.f,0.f,0.f};
                #pragma unroll
                for (int kt = 0; kt < 6; kt++) acc = MFMA16(afrag(wsw + WP_OFF, 6, kt, rt, lane), bfr[kt], acc);
                int cb = rt * 16 + ((lane >> 4) << 2);
                float4 b4 = *(const float4*)&bpj[cb];
                float4 old = *(const float4*)&yout[ft * 96 + cb];
                float4 res;
                res.x = old.x + acc[0] + b4.x;
                res.y = old.y + acc[1] + b4.y;
                res.z = old.z + acc[2] + b4.z;
                res.w = old.w + acc[3] + b4.w;
                *(float4*)&yout[ft * 96 + cb] = res;
            }
        }
        __syncthreads();   // before next qt overwrites Qs
    }
}

// ---------------- MLP (MFMA): d_out = y + W2(gelu(W1 ln(y)+b1))+b2, in place ----------------
__global__ __launch_bounds__(512) void k_mlp(const float* __restrict__ y,
    const float* __restrict__ g2, const float* __restrict__ b2v,
    const __bf16* __restrict__ wsw, const float* __restrict__ b1m,
    const float* __restrict__ b2m, float* __restrict__ outp){
    __shared__ __bf16 yln[64][104];
    __shared__ __bf16 hsm[64][392];
    const int tid = threadIdx.x, lane = tid & 63, w = tid >> 6;
    const int t0 = blockIdx.x * 64;
    {   // LN stage
        int row = tid >> 3, sub = tid & 7;
        const float* yp = y + (t0 + row) * 96 + sub * 12;
        float v[12]; float s = 0.f, ss = 0.f;
        #pragma unroll
        for (int i = 0; i < 3; i++){
            float4 t = ((const float4*)yp)[i];
            v[4*i] = t.x; v[4*i+1] = t.y; v[4*i+2] = t.z; v[4*i+3] = t.w;
            s += t.x + t.y + t.z + t.w;
            ss += t.x*t.x + t.y*t.y + t.z*t.z + t.w*t.w;
        }
        #pragma unroll
        for (int m = 1; m < 8; m <<= 1){ s += __shfl_xor(s, m); ss += __shfl_xor(ss, m); }
        float mu = s * (1.f/96.f), var = ss * (1.f/96.f) - mu*mu, rs = rsqrtf(var + 1e-5f);
        #pragma unroll
        for (int i = 0; i < 3; i++){
            bf16x4 t;
            #pragma unroll
            for (int jj = 0; jj < 4; jj++){
                int c = sub*12 + 4*i + jj;
                t[jj] = (__bf16)((v[4*i+jj] - mu) * rs * g2[c] + b2v[c]);
            }
            *(bf16x4*)&yln[row][sub*12 + 4*i] = t;
        }
    }
    __syncthreads();
    const int ct = w & 3, rh = w >> 2;
    const int tok = ct * 16 + (lane & 15);
    {   // GEMM1: h^T = W1^T @ yln^T, gelu -> hsm row-major
        bf16x8 bfr[3];
        #pragma unroll
        for (int kt = 0; kt < 3; kt++) bfr[kt] = *(const bf16x8*)&yln[tok][kt*32 + (lane>>4)*8];
        #pragma unroll
        for (int i = 0; i < 12; i++){
            int rt = rh * 12 + i;
            f32x4 acc = {0.f,0.f,0.f,0.f};
            #pragma unroll
            for (int kt = 0; kt < 3; kt++) acc = MFMA16(afrag(wsw + W1_OFF, 24, kt, rt, lane), bfr[kt], acc);
            int cb = rt * 16 + ((lane >> 4) << 2);
            float4 b4 = *(const float4*)&b1m[cb];
            bf16x4 t;
            t[0] = (__bf16)gelu_exact(acc[0] + b4.x);
            t[1] = (__bf16)gelu_exact(acc[1] + b4.y);
            t[2] = (__bf16)gelu_exact(acc[2] + b4.z);
            t[3] = (__bf16)gelu_exact(acc[3] + b4.w);
            *(bf16x4*)&hsm[tok][cb] = t;
        }
    }
    __syncthreads();
    {   // GEMM2: o^T = W2^T @ h^T ; residual add, in-place
        bf16x8 bfr[12];
        #pragma unroll
        for (int kt = 0; kt < 12; kt++) bfr[kt] = *(const bf16x8*)&hsm[tok][kt*32 + (lane>>4)*8];
        #pragma unroll
        for (int i = 0; i < 3; i++){
            int rt = rh * 3 + i;
            f32x4 acc = {0.f,0.f,0.f,0.f};
            #pragma unroll
            for (int kt = 0; kt < 12; kt++) acc = MFMA16(afrag(wsw + W2_OFF, 6, kt, rt, lane), bfr[kt], acc);
            int cb = rt * 16 + ((lane >> 4) << 2);
            float4 b4 = *(const float4*)&b2m[cb];
            float4 old = *(const float4*)&outp[(t0 + tok) * 96 + cb];
            float4 res;
            res.x = old.x + acc[0] + b4.x;
            res.y = old.y + acc[1] + b4.y;
            res.z = old.z + acc[2] + b4.z;
            res.w = old.w + acc[3] + b4.w;
            *(float4*)&outp[(t0 + tok) * 96 + cb] = res;
        }
    }
}

extern "C" void kernel_launch(void* const* d_in, const int* in_sizes, int n_in,
                              void* d_out, int out_size, void* d_ws, size_t ws_size,
                              hipStream_t stream){
    const float* x    = (const float*)d_in[0];
    const float* xd   = (const float*)d_in[1];
    const float* g1   = (const float*)d_in[2];
    const float* b1v  = (const float*)d_in[3];
    const float* Wkv  = (const float*)d_in[4];
    const float* bkv  = (const float*)d_in[5];
    const float* Wq   = (const float*)d_in[6];
    const float* bq   = (const float*)d_in[7];
    const float* Wp   = (const float*)d_in[8];
    const float* bpj  = (const float*)d_in[9];
    const float* btab = (const float*)d_in[10];
    const float* eg   = (const float*)d_in[11];
    const float* eb   = (const float*)d_in[12];
    const float* dw   = (const float*)d_in[13];
    const float* db   = (const float*)d_in[14];
    const float* g2   = (const float*)d_in[15];
    const float* b2v  = (const float*)d_in[16];
    const float* W1   = (const float*)d_in[17];
    const float* b1m  = (const float*)d_in[18];
    const float* W2   = (const float*)d_in[19];
    const float* b2m  = (const float*)d_in[20];
    (void)in_sizes; (void)n_in; (void)out_size; (void)ws_size;

    float*   out  = (float*)d_out;
    float*   bias = (float*)d_ws;
    __bf16*  wsw  = (__bf16*)((char*)d_ws + BIAS_BYTES);

    k_prep  <<<2064, 256, 0, stream>>>(btab, Wkv, Wq, Wp, dw, W1, W2, bias, wsw);
    k_deconv<<<512, 512, 0, stream>>>(x, eg, eb, wsw, db, out);
    k_attn  <<<512, 512, 0, stream>>>(x, xd, g1, b1v, bkv, bq, bpj, wsw, bias, out);
    k_mlp   <<<4096, 512, 0, stream>>>(out, g2, b2v, wsw, b1m, b2m, out);
}